// Round 9
// baseline (378.986 us; speedup 1.0000x reference)
//
#include <hip/hip_runtime.h>

typedef __bf16 bf16x8 __attribute__((ext_vector_type(8)));
typedef float  f32x4  __attribute__((ext_vector_type(4)));
typedef unsigned short u16x8 __attribute__((ext_vector_type(8)));

// Problem constants
constexpr int BB    = 16;
constexpr int TT    = 12;
constexpr int NN    = 307;
constexpr int TN    = TT * NN;        // 3684
constexpr int ROWSX = BB * TT * NN;   // 58944
constexpr int ROWSH = BB * NN;        // 4912
constexpr int SST1  = 3712;           // sag row stride (464 x b128 chunks)
constexpr int SSTR  = 3840;           // xnT row stride
constexpr float SCALE = 0.125f;

__device__ __forceinline__ float wred_sum(float v) {
#pragma unroll
    for (int m = 32; m > 0; m >>= 1) v += __shfl_xor(v, m, 64);
    return v;
}

// ---------------------------------------------------------------------------
// Fold q/k projections: dg = q.k = qt.x_ + c
// ---------------------------------------------------------------------------
__global__ void fold_k(const float* __restrict__ qw, const float* __restrict__ qb,
                       const float* __restrict__ kw, const float* __restrict__ kb,
                       float* __restrict__ M, float* __restrict__ b2,
                       float* __restrict__ vv, float* __restrict__ cc) {
    int e = blockIdx.x, d = threadIdx.x;
    float acc = 0.f;
    for (int dp = 0; dp < 64; ++dp) acc += qw[dp * 64 + e] * kw[dp * 64 + d];
    M[e * 64 + d] = acc;
    float vp = wred_sum(qw[d * 64 + e] * kb[d]);
    if (d == 0) vv[e] = vp;
    if (e == 0) {
        float b = 0.f;
        for (int dp = 0; dp < 64; ++dp) b += qb[dp] * kw[dp * 64 + d];
        b2[d] = b;
        float cp = wred_sum(qb[d] * kb[d]);
        if (d == 0) *cc = cp;
    }
}

// ---------------------------------------------------------------------------
// fc1w/fc2w fp32 -> bf16
// ---------------------------------------------------------------------------
__global__ void wconv_k(const float* __restrict__ fc1w, const float* __restrict__ fc2w,
                        __bf16* __restrict__ fc1b16, __bf16* __restrict__ fc2b16) {
    int i = blockIdx.x * 256 + threadIdx.x;
    if (i < 16384) fc1b16[i] = (__bf16)fc1w[i];
    else fc2b16[i - 16384] = (__bf16)fc2w[i - 16384];
}

// ---------------------------------------------------------------------------
// LayerNorm -> xnb (bf16) + y32 (fp32, t==11 slab)
// ---------------------------------------------------------------------------
__global__ __launch_bounds__(256) void ln_k(const float* __restrict__ x,
                                            const float* __restrict__ g,
                                            const float* __restrict__ b,
                                            __bf16* __restrict__ xnb,
                                            float* __restrict__ y32) {
    int w = threadIdx.x >> 6, l = threadIdx.x & 63;
    int r = blockIdx.x * 4 + w;
    if (r >= ROWSX) return;
    float val = x[r * 64 + l];
    float mu  = wred_sum(val) * (1.f / 64.f);
    float dv  = val - mu;
    float var = wred_sum(dv * dv) * (1.f / 64.f);
    float xv  = dv * rsqrtf(var + 1e-5f) * g[l] + b[l];
    xnb[(size_t)r * 64 + l] = (__bf16)xv;
    int t = (r / NN) % TT;
    if (t == TT - 1) {
        int bbv = r / (NN * TT), n = r % NN;
        y32[(bbv * NN + n) * 64 + l] = xv;
    }
}

// ---------------------------------------------------------------------------
// Transpose xnb[b,j,d] -> xnT[b,d,j] (stride SSTR; j>=TN zero within tiles)
// ---------------------------------------------------------------------------
__global__ __launch_bounds__(256) void t_k(const __bf16* __restrict__ xnb,
                                           __bf16* __restrict__ xnT) {
    __shared__ unsigned short tile[64][65];
    int bb = blockIdx.y, j0 = blockIdx.x * 64, t = threadIdx.x;
    const unsigned short* src = (const unsigned short*)xnb;
    unsigned short* dst = (unsigned short*)xnT;
#pragma unroll
    for (int i = 0; i < 16; ++i) {
        int f = t + 256 * i, jr = f >> 6, dc = f & 63;
        int j = j0 + jr;
        tile[jr][dc] = (j < TN) ? src[((size_t)bb * TN + j) * 64 + dc] : (unsigned short)0;
    }
    __syncthreads();
#pragma unroll
    for (int i = 0; i < 16; ++i) {
        int f = t + 256 * i, d = f >> 6, jj = f & 63;
        dst[((size_t)bb * 64 + d) * SSTR + j0 + jj] = tile[jj][d];
    }
}

// ---------------------------------------------------------------------------
// qt[row] = y_ @ M + b2 (bf16);  cq[row] = y_.v + cc
// ---------------------------------------------------------------------------
__global__ __launch_bounds__(256) void qt_k(const float* __restrict__ y32,
                                            const float* __restrict__ M,
                                            const float* __restrict__ b2,
                                            const float* __restrict__ vv,
                                            const float* __restrict__ ccp,
                                            __bf16* __restrict__ qtb,
                                            float* __restrict__ cq) {
    int w = threadIdx.x >> 6, l = threadIdx.x & 63;
    int rr = blockIdx.x * 4 + w;
    if (rr >= ROWSH) return;
    float y = y32[rr * 64 + l];
    float acc = b2[l];
#pragma unroll
    for (int e = 0; e < 64; ++e) acc += __shfl(y, e, 64) * M[e * 64 + l];
    qtb[(size_t)rr * 64 + l] = (__bf16)acc;
    float cp = wred_sum(y * vv[l]);
    if (l == 0) cq[rr] = cp + *ccp;
}

// ---------------------------------------------------------------------------
// Score GEMM via MFMA. stg staged via LDS float4; epilogue packs bf16
// weights, transposes through LDS, stores coalesced b128.
// ---------------------------------------------------------------------------
__global__ __launch_bounds__(256) void score_k(const __bf16* __restrict__ qtb,
                                               const float* __restrict__ cq,
                                               const __bf16* __restrict__ xnb,
                                               const float* __restrict__ stg,
                                               __bf16* __restrict__ sag) {
    __shared__ float sstg[64 * 132];   // 33 KB; phase-2 overlay: u16 wb[64][136]
    int bb = blockIdx.z, n0 = blockIdx.y * 64, j0 = blockIdx.x * 128;
    int t = threadIdx.x;
    int w = t >> 6, lane = t & 63;
    int m16 = lane & 15, q4 = lane >> 4;

#pragma unroll
    for (int i = 0; i < 8; ++i) {
        int flat = t + i * 256;
        int row = flat >> 5, c4 = (flat & 31) * 4;
        int n = n0 + row;
        float4 v = {0.f, 0.f, 0.f, 0.f};
        if (n < NN) {
            size_t rb = (size_t)(bb * NN + n) * TN;
            int j = j0 + c4;
            if (j + 3 < TN) v = *(const float4*)(stg + rb + j);
            else {
                if (j + 0 < TN) v.x = stg[rb + j + 0];
                if (j + 1 < TN) v.y = stg[rb + j + 1];
                if (j + 2 < TN) v.z = stg[rb + j + 2];
                if (j + 3 < TN) v.w = stg[rb + j + 3];
            }
        }
        *(float4*)&sstg[row * 132 + c4] = v;
    }

    const bf16x8* ap = (const bf16x8*)(qtb + ((size_t)bb * NN + n0 + w * 16 + m16) * 64);
    bf16x8 a0 = ap[q4], a1 = ap[q4 + 4];
    f32x4 acc[8];
#pragma unroll
    for (int jt = 0; jt < 8; ++jt) {
        const bf16x8* bp = (const bf16x8*)(xnb + ((size_t)bb * TN + j0 + jt * 16 + m16) * 64);
        bf16x8 b0 = bp[q4], b1 = bp[q4 + 4];
        f32x4 c = {0.f, 0.f, 0.f, 0.f};
        c = __builtin_amdgcn_mfma_f32_16x16x32_bf16(a0, b0, c, 0, 0, 0);
        c = __builtin_amdgcn_mfma_f32_16x16x32_bf16(a1, b1, c, 0, 0, 0);
        acc[jt] = c;
    }
    int nbase = n0 + w * 16 + q4 * 4;
    float cn[4];
#pragma unroll
    for (int r = 0; r < 4; ++r) {
        int n = nbase + r;
        cn[r] = (n < NN) ? cq[bb * NN + n] : 0.f;
    }
    __syncthreads();

    u16x8 wvr[4];
#pragma unroll
    for (int r = 0; r < 4; ++r) {
        int nloc = w * 16 + q4 * 4 + r;
#pragma unroll
        for (int jt = 0; jt < 8; ++jt) {
            int j = j0 + jt * 16 + m16;
            float sv = sstg[nloc * 132 + jt * 16 + m16];
            float dg = (acc[jt][r] + cn[r]) * SCALE;
            float s  = 1.f / (1.f + __expf(-dg));
            float wv = (j < TN) ? s * sv * SCALE : 0.f;
            __bf16 wb16 = (__bf16)wv;
            wvr[r][jt] = *(unsigned short*)&wb16;
        }
    }
    __syncthreads();

    unsigned short* wb = (unsigned short*)sstg;   // stride 136
#pragma unroll
    for (int r = 0; r < 4; ++r) {
        int nloc = w * 16 + q4 * 4 + r;
#pragma unroll
        for (int jt = 0; jt < 8; ++jt)
            wb[nloc * 136 + jt * 16 + m16] = wvr[r][jt];
    }
    __syncthreads();

#pragma unroll
    for (int i = 0; i < 4; ++i) {
        int chunk = t + i * 256;
        int row = chunk >> 4, c8 = (chunk & 15) * 8;
        int n = n0 + row;
        if (n < NN) {
            u16x8 v = *(const u16x8*)&wb[row * 136 + c8];
            *(u16x8*)((unsigned short*)sag + (size_t)(bb * NN + n) * SST1 + j0 + c8) = v;
        }
    }
}

// ---------------------------------------------------------------------------
// attn v4: 16 rows/block (512 thr), TWO rows per wave loaded upfront (2x
// memory-level parallelism), fused dual binary search (two independent
// VALU chains interleaved), PV in two phases reusing one 59.5 KB buffer.
// ---------------------------------------------------------------------------
__global__ __launch_bounds__(512, 4) void attn_k(const __bf16* __restrict__ sagB,
                                                 const __bf16* __restrict__ xnT,
                                                 const float* __restrict__ y32,
                                                 const int* __restrict__ topk_p,
                                                 float* __restrict__ h) {
    __shared__ unsigned short sg[8][3720];   // 59.5 KB
    __shared__ float red[4][8][16];          // 2 KB
    int t = threadIdx.x;
    int bb = blockIdx.y, n0 = blockIdx.x * 16;
    int wid = t >> 6, lane = t & 63;
    int m16 = lane & 15, q4 = lane >> 4;

    int topkv = *topk_p;
    bool selAll = (topkv <= 0);
    int kk = 0;
    if (!selAll) {
        kk = (topkv < 5) ? topkv * NN : topkv;
        if (kk > TN) kk = TN;
    }

    // ---- load both rows upfront: 16 b128 loads in flight ----
    int nA = n0 + wid, nB = n0 + 8 + wid;
    const u16x8* srcA = (const u16x8*)((const unsigned short*)sagB +
                                       (size_t)(bb * NN + min(nA, NN - 1)) * SST1);
    const u16x8* srcB = (const u16x8*)((const unsigned short*)sagB +
                                       (size_t)(bb * NN + min(nB, NN - 1)) * SST1);
    u16x8 va[8], vb[8];
#pragma unroll
    for (int ci = 0; ci < 8; ++ci) {
        int c = lane + (ci << 6);
        u16x8 v0 = {0, 0, 0, 0, 0, 0, 0, 0}, v1 = v0;
        if (c < 464) { v0 = srcA[ci * 64 + lane]; v1 = srcB[ci * 64 + lane]; }
        va[ci] = v0; vb[ci] = v1;
    }

    // ---- row maxima ----
    int vmA = 0, vmB = 0;
#pragma unroll
    for (int ci = 0; ci < 8; ++ci)
#pragma unroll
        for (int e = 0; e < 8; ++e) {
            vmA = max(vmA, (int)va[ci][e]);
            vmB = max(vmB, (int)vb[ci][e]);
        }
#pragma unroll
    for (int m = 32; m > 0; m >>= 1) {
        vmA = max(vmA, __shfl_xor(vmA, m, 64));
        vmB = max(vmB, __shfl_xor(vmB, m, 64));
    }
    float vmaxA = __uint_as_float(((unsigned)vmA) << 16);
    float vmaxB = __uint_as_float(((unsigned)vmB) << 16);

    // ---- fused dual binary search (two independent chains) ----
    unsigned thrA = 0, thrB = 0;
    if (!selAll) {
        unsigned loA = 0, hiA = (unsigned)vmA;
        unsigned loB = 0, hiB = (unsigned)vmB;
        while (loA < hiA || loB < hiB) {
            bool doA = loA < hiA, doB = loB < hiB;
            unsigned midA = (loA + hiA) >> 1, midB = (loB + hiB) >> 1;
            int cntA = 0, cntB = 0;
#pragma unroll
            for (int ci = 0; ci < 8; ++ci)
#pragma unroll
                for (int e = 0; e < 8; ++e) {
                    if (doA) cntA += (int)__popcll(__ballot((unsigned)va[ci][e] > midA));
                    if (doB) cntB += (int)__popcll(__ballot((unsigned)vb[ci][e] > midB));
                }
            if (doA) { if (cntA < kk) hiA = midA; else loA = midA + 1; }
            if (doB) { if (cntB < kk) hiB = midB; else loB = midB + 1; }
        }
        thrA = loA; thrB = loB;
    }

    // ---- softmax (exp, sum, normalize) for both rows, in registers ----
#define SOFTMAX_ROW(VV, THR, VMX)                                                \
    {                                                                            \
        float local = 0.f;                                                       \
        _Pragma("unroll") for (int ci = 0; ci < 8; ++ci) {                       \
            int c = lane + (ci << 6);                                            \
            int nvv = (c < 460) ? 8 : ((c == 460) ? 4 : 0);                      \
            _Pragma("unroll") for (int e = 0; e < 8; ++e) {                      \
                unsigned u = VV[ci][e];                                          \
                bool sel = selAll ? (e < nvv) : (u > THR);                       \
                float ev = sel ? __expf(__uint_as_float(u << 16) - VMX) : 0.f;   \
                local += ev;                                                     \
                __bf16 eb = (__bf16)ev;                                          \
                VV[ci][e] = *(unsigned short*)&eb;                               \
            }                                                                    \
        }                                                                        \
        local = wred_sum(local);                                                 \
        bool uni = !(local > 0.f);                                               \
        float inv = uni ? 0.f : 1.f / local;                                     \
        float uval = 1.f / (float)TN;                                            \
        _Pragma("unroll") for (int ci = 0; ci < 8; ++ci) {                       \
            int c = lane + (ci << 6);                                            \
            int nvv = (c < 460) ? 8 : ((c == 460) ? 4 : 0);                      \
            _Pragma("unroll") for (int e = 0; e < 8; ++e) {                      \
                unsigned short us = VV[ci][e];                                   \
                float ev = (float)(*(__bf16*)&us);                               \
                float wv = uni ? ((e < nvv) ? uval : 0.f) : ev * inv;            \
                __bf16 ob = (__bf16)wv;                                          \
                VV[ci][e] = *(unsigned short*)&ob;                               \
            }                                                                    \
        }                                                                        \
    }

    SOFTMAX_ROW(va, thrA, vmaxA)
    SOFTMAX_ROW(vb, thrB, vmaxB)
#undef SOFTMAX_ROW

#define WRITE_ROW(VV)                                                            \
    _Pragma("unroll") for (int ci = 0; ci < 8; ++ci) {                           \
        int c = lane + (ci << 6);                                                \
        if (c < 464) *(u16x8*)&sg[wid][c * 8] = VV[ci];                          \
    }

    // ---- PV phase macro: A-rows from sg, d-split(4) x K-split(2) ----
    int dg = wid & 3, kh = wid >> 2;
    const __bf16* bbase = xnT + ((size_t)bb * 64 + dg * 16 + m16) * SSTR + q4 * 8;
    int kbeg = kh * 1856;
    bf16x8 zf;
#pragma unroll
    for (int e = 0; e < 8; ++e) zf[e] = (__bf16)0.f;

#define PV_PHASE(NBASE)                                                          \
    {                                                                            \
        f32x4 acc0 = {0.f, 0.f, 0.f, 0.f}, acc1 = {0.f, 0.f, 0.f, 0.f};          \
        for (int ks = 0; ks < 58; ks += 2) {                                     \
            int k0 = kbeg + ks * 32, k1 = k0 + 32;                               \
            bf16x8 a0 = (m16 < 8) ? *(const bf16x8*)&sg[m16][k0 + q4 * 8] : zf;  \
            bf16x8 a1 = (m16 < 8) ? *(const bf16x8*)&sg[m16][k1 + q4 * 8] : zf;  \
            bf16x8 b0 = *(const bf16x8*)(bbase + k0);                            \
            bf16x8 b1 = *(const bf16x8*)(bbase + k1);                            \
            acc0 = __builtin_amdgcn_mfma_f32_16x16x32_bf16(a0, b0, acc0, 0, 0, 0); \
            acc1 = __builtin_amdgcn_mfma_f32_16x16x32_bf16(a1, b1, acc1, 0, 0, 0); \
        }                                                                        \
        if (kh == 0 && q4 < 2) {                                                 \
            _Pragma("unroll") for (int r = 0; r < 4; ++r)                        \
                red[dg][q4 * 4 + r][m16] = acc0[r] + acc1[r];                    \
        }                                                                        \
        __syncthreads();                                                         \
        if (kh == 1 && q4 < 2) {                                                 \
            _Pragma("unroll") for (int r = 0; r < 4; ++r) {                      \
                int row = q4 * 4 + r;                                            \
                int nn2 = (NBASE) + row;                                         \
                if (nn2 < NN) {                                                  \
                    size_t o = (size_t)(bb * NN + nn2) * 64 + dg * 16 + m16;     \
                    h[o] = acc0[r] + acc1[r] + red[dg][row][m16] + y32[o];       \
                }                                                                \
            }                                                                    \
        }                                                                        \
    }

    WRITE_ROW(va)
    __syncthreads();
    PV_PHASE(n0)            // writes h rows n0..n0+7; barrier inside frees sg
    WRITE_ROW(vb)
    __syncthreads();
    PV_PHASE(n0 + 8)        // writes h rows n0+8..n0+15
#undef PV_PHASE
#undef WRITE_ROW
}

// ---------------------------------------------------------------------------
// FFN via MFMA bf16
// ---------------------------------------------------------------------------
__global__ __launch_bounds__(256) void ffn_k(const float* __restrict__ h,
                                             const float* __restrict__ g,
                                             const float* __restrict__ bln,
                                             const __bf16* __restrict__ fc1b16,
                                             const float* __restrict__ fc1b,
                                             const __bf16* __restrict__ fc2b16,
                                             const float* __restrict__ fc2b,
                                             float* __restrict__ out) {
    __shared__ __bf16 zb[16 * 68];
    __shared__ __bf16 ab[16 * 264];
    int t = threadIdx.x, r0 = blockIdx.x * 16;
    int wid = t >> 6, lane = t & 63;
    int m16 = lane & 15, q4 = lane >> 4;

#pragma unroll
    for (int q = 0; q < 4; ++q) {
        int rl = wid * 4 + q;
        float val = h[(size_t)(r0 + rl) * 64 + lane];
        float mu  = wred_sum(val) * (1.f / 64.f);
        float dv  = val - mu;
        float var = wred_sum(dv * dv) * (1.f / 64.f);
        zb[rl * 68 + lane] = (__bf16)(dv * rsqrtf(var + 1e-5f) * g[lane] + bln[lane]);
    }
    __syncthreads();

    bf16x8 a0 = *(const bf16x8*)&zb[m16 * 68 + q4 * 8];
    bf16x8 a1 = *(const bf16x8*)&zb[m16 * 68 + 32 + q4 * 8];
#pragma unroll
    for (int jt2 = 0; jt2 < 4; ++jt2) {
        int j0t = (wid * 4 + jt2) * 16;
        const __bf16* bp = fc1b16 + (size_t)(j0t + m16) * 64 + q4 * 8;
        f32x4 c = {0.f, 0.f, 0.f, 0.f};
        c = __builtin_amdgcn_mfma_f32_16x16x32_bf16(a0, *(const bf16x8*)bp, c, 0, 0, 0);
        c = __builtin_amdgcn_mfma_f32_16x16x32_bf16(a1, *(const bf16x8*)(bp + 32), c, 0, 0, 0);
        int j = j0t + m16;
        float bias = fc1b[j];
#pragma unroll
        for (int r = 0; r < 4; ++r)
            ab[(q4 * 4 + r) * 264 + j] = (__bf16)fmaxf(c[r] + bias, 0.f);
    }
    __syncthreads();

    f32x4 c2a = {0.f, 0.f, 0.f, 0.f}, c2b = {0.f, 0.f, 0.f, 0.f};
    const __bf16* b2p = fc2b16 + (size_t)(wid * 16 + m16) * 256 + q4 * 8;
#pragma unroll
    for (int k8 = 0; k8 < 8; k8 += 2) {
        bf16x8 aa0 = *(const bf16x8*)&ab[m16 * 264 + k8 * 32 + q4 * 8];
        bf16x8 aa1 = *(const bf16x8*)&ab[m16 * 264 + (k8 + 1) * 32 + q4 * 8];
        c2a = __builtin_amdgcn_mfma_f32_16x16x32_bf16(aa0, *(const bf16x8*)(b2p + k8 * 32), c2a, 0, 0, 0);
        c2b = __builtin_amdgcn_mfma_f32_16x16x32_bf16(aa1, *(const bf16x8*)(b2p + (k8 + 1) * 32), c2b, 0, 0, 0);
    }
    int d = wid * 16 + m16;
    float bias2 = fc2b[d];
#pragma unroll
    for (int r = 0; r < 4; ++r) {
        size_t row = (size_t)(r0 + q4 * 4 + r);
        out[row * 64 + d] = h[row * 64 + d] + c2a[r] + c2b[r] + bias2;
    }
}

extern "C" void kernel_launch(void* const* d_in, const int* in_sizes, int n_in,
                              void* d_out, int out_size, void* d_ws, size_t ws_size,
                              hipStream_t stream) {
    const float* x    = (const float*)d_in[0];
    const float* stg  = (const float*)d_in[1];
    const int*   topk = (const int*)d_in[2];
    const float* qw   = (const float*)d_in[3];
    const float* qb   = (const float*)d_in[4];
    const float* kw   = (const float*)d_in[5];
    const float* kb   = (const float*)d_in[6];
    const float* lng  = (const float*)d_in[7];
    const float* lnb  = (const float*)d_in[8];
    const float* flng = (const float*)d_in[9];
    const float* flnb = (const float*)d_in[10];
    const float* fc1w = (const float*)d_in[11];
    const float* fc1b = (const float*)d_in[12];
    const float* fc2w = (const float*)d_in[13];
    const float* fc2b = (const float*)d_in[14];
    float* out = (float*)d_out;

    float* ws = (float*)d_ws;
    __bf16* xnb = (__bf16*)ws;                 // ROWSX*64 bf16 = 1,886,208 f
    float* p1   = ws + 1886208;
    __bf16* xnT = (__bf16*)p1;                 // 16*64*3840 bf16 = 1,966,080 f
    float* p2   = p1 + 1966080;
    __bf16* qtb = (__bf16*)p2;                 // 4928*64 bf16 = 157,696 f
    float* y32  = p2 + 157696;                 // 314,368 f
    float* cq   = y32 + 314368;                // 4,928 f
    float* M    = cq + 4928;                   // 4,096
    float* b2   = M + 4096;                    // 64
    float* vv   = b2 + 64;                     // 64
    float* cc   = vv + 64;                     // 16
    __bf16* fc1b16 = (__bf16*)(cc + 16);       // 8,192 f
    __bf16* fc2b16 = (__bf16*)((float*)fc1b16 + 8192);  // 8,192 f
    __bf16* sag = (__bf16*)((float*)fc2b16 + 8192);     // ROWSH*3712 bf16 = 9,116,672 f
    float* h    = (float*)sag + 9116672;       // 314,368 f

    fold_k<<<64, 64, 0, stream>>>(qw, qb, kw, kb, M, b2, vv, cc);
    wconv_k<<<128, 256, 0, stream>>>(fc1w, fc2w, fc1b16, fc2b16);
    ln_k<<<(ROWSX + 3) / 4, 256, 0, stream>>>(x, lng, lnb, xnb, y32);
    t_k<<<dim3((TN + 63) / 64, BB), 256, 0, stream>>>(xnb, xnT);
    qt_k<<<(ROWSH + 3) / 4, 256, 0, stream>>>(y32, M, b2, vv, cc, qtb, cq);
    score_k<<<dim3((TN + 127) / 128, (NN + 63) / 64, BB), 256, 0, stream>>>(qtb, cq, xnb, stg, sag);
    attn_k<<<dim3((NN + 15) / 16, BB), 512, 0, stream>>>(sag, xnT, y32, topk, h);
    ffn_k<<<ROWSH / 16, 256, 0, stream>>>(h, flng, flnb, fc1b16, fc1b, fc2b16, fc2b, out);
}